// Round 5
// baseline (238.261 us; speedup 1.0000x reference)
//
#include <hip/hip_runtime.h>

// Output layout (float32, flat):
//   [0 .. 25165824)  mask_a : (8, 12, 512, 512)
//   [25165824 .. )   mask_b : (8, 12, 512, 512)
// Channel groups (cc/3): 0=ones, 1=ABA checkerboard (i%2==j%2),
//                        2=row parity (i%2), 3=col parity (j%2).
// mask_b = 1 - mask_a for every group.
//
// HARNESS NOTE: out_size is the FLOAT COUNT (50,331,648), not bytes.
//
// DIAGNOSTIC ROUND: round-0 kernel (best measured, 215.4 us), launched TWICE.
// Writes are idempotent so output is unchanged; the dur_us delta vs round 0
// (fill-normalized) measures the kernel's true marginal duration, which the
// top-5-only rocprof view cannot show. ~250us => kernel is roofline-bound
// (~35us) and harness gaps dominate; ~305us => kernel is ~90us with headroom.

__global__ __launch_bounds__(256) void picmix_kernel(float4* __restrict__ out,
                                                     unsigned int n4) {
    unsigned int idx4 = blockIdx.x * blockDim.x + threadIdx.x;
    if (idx4 >= n4) return;
    unsigned int id = idx4 * 4u;                 // flat float index (multiple of 4)
    unsigned int t  = (id >= 25165824u) ? 1u : 0u;   // 0 = mask_a, 1 = mask_b
    unsigned int cc = (id >> 18) % 12u;              // channel 0..11 (HW = 2^18)
    unsigned int g  = cc / 3u;                       // rule group 0..3
    unsigned int ip = (id >> 9) & 1u;                // row parity (W = 512 = 2^9)
    // column parities within this float4 are (0,1,0,1): id%512 is a multiple of 4.

    float va0, va1;  // mask_a value at even/odd column
    if (g == 0u)      { va0 = 1.f;              va1 = 1.f; }
    else if (g == 1u) { va0 = ip ? 0.f : 1.f;   va1 = ip ? 1.f : 0.f; }
    else if (g == 2u) { va0 = (float)ip;        va1 = (float)ip; }
    else              { va0 = 0.f;              va1 = 1.f; }

    float v0 = t ? 1.f - va0 : va0;
    float v1 = t ? 1.f - va1 : va1;
    out[idx4] = make_float4(v0, v1, v0, v1);
}

extern "C" void kernel_launch(void* const* d_in, const int* in_sizes, int n_in,
                              void* d_out, int out_size, void* d_ws, size_t ws_size,
                              hipStream_t stream) {
    // Inputs img_a / img_b are unused: the reference's outputs are
    // deterministic parity masks independent of the image contents.
    (void)d_in; (void)in_sizes; (void)n_in; (void)d_ws; (void)ws_size;
    unsigned int n4 = (unsigned int)(out_size / 4);   // out_size = FLOAT count
    unsigned int blocks = (n4 + 255u) / 256u;         // 49,152 blocks
    // Launch TWICE (diagnostic): second launch adds exactly one kernel
    // duration to the timed graph; writes are idempotent.
    picmix_kernel<<<blocks, 256, 0, stream>>>((float4*)d_out, n4);
    picmix_kernel<<<blocks, 256, 0, stream>>>((float4*)d_out, n4);
}

// Round 6
// 213.567 us; speedup vs baseline: 1.1156x; 1.1156x over previous
//
#include <hip/hip_runtime.h>

// Output layout (float32, flat):
//   [0 .. 25165824)  mask_a : (8, 12, 512, 512)
//   [25165824 .. )   mask_b : (8, 12, 512, 512)
// Channel groups (cc/3): 0=ones, 1=ABA checkerboard (i%2==j%2),
//                        2=row parity (i%2), 3=col parity (j%2).
// mask_b = 1 - mask_a for every group.
//
// HARNESS NOTE: out_size is the FLOAT COUNT (50,331,648), not bytes.
//
// STATUS (round-5 diagnostic, 2x-launch differential): kernel marginal
// duration ~28.5 us vs pure-write roofline ~30 us (201 MB @ 6.7 TB/s fill
// BW) => at the memory roofline. dur_us is dominated by harness-fixed
// cost: ~120-130 us poison fill + ~62 us reset-dispatch gaps. Structural
// variants (grid-stride, nontemporal, dual-stream) were all indistinguishable
// because the kernel was already at the wall.

__global__ __launch_bounds__(256) void picmix_kernel(float4* __restrict__ out,
                                                     unsigned int n4) {
    unsigned int idx4 = blockIdx.x * blockDim.x + threadIdx.x;
    if (idx4 >= n4) return;
    unsigned int id = idx4 * 4u;                 // flat float index (multiple of 4)
    unsigned int t  = (id >= 25165824u) ? 1u : 0u;   // 0 = mask_a, 1 = mask_b
    unsigned int cc = (id >> 18) % 12u;              // channel 0..11 (HW = 2^18)
    unsigned int g  = cc / 3u;                       // rule group 0..3
    unsigned int ip = (id >> 9) & 1u;                // row parity (W = 512 = 2^9)
    // column parities within this float4 are (0,1,0,1): id%512 is a multiple of 4.

    float va0, va1;  // mask_a value at even/odd column
    if (g == 0u)      { va0 = 1.f;              va1 = 1.f; }
    else if (g == 1u) { va0 = ip ? 0.f : 1.f;   va1 = ip ? 1.f : 0.f; }
    else if (g == 2u) { va0 = (float)ip;        va1 = (float)ip; }
    else              { va0 = 0.f;              va1 = 1.f; }

    float v0 = t ? 1.f - va0 : va0;
    float v1 = t ? 1.f - va1 : va1;
    out[idx4] = make_float4(v0, v1, v0, v1);
}

extern "C" void kernel_launch(void* const* d_in, const int* in_sizes, int n_in,
                              void* d_out, int out_size, void* d_ws, size_t ws_size,
                              hipStream_t stream) {
    // Inputs img_a / img_b are unused: the reference's outputs are
    // deterministic parity masks independent of the image contents.
    (void)d_in; (void)in_sizes; (void)n_in; (void)d_ws; (void)ws_size;
    unsigned int n4 = (unsigned int)(out_size / 4);   // out_size = FLOAT count
    unsigned int blocks = (n4 + 255u) / 256u;         // 49,152 blocks
    picmix_kernel<<<blocks, 256, 0, stream>>>((float4*)d_out, n4);
}